// Round 5
// baseline (257.381 us; speedup 1.0000x reference)
//
#include <hip/hip_runtime.h>

#define N_NODES 50000
#define N_EDGES 640000
#define D 128
#define NBKT 782            // ceil(50000/64) buckets of 64 dst nodes
#define EPB 8192            // edges per bin_scatter block
#define NSB ((N_EDGES + EPB - 1) / EPB)   // 79 scatter blocks
#define CAP 2048            // max records per bucket (mean 819, 40+ sigma headroom)

// round-to-nearest-even f32 -> bf16
static __device__ __forceinline__ unsigned short f2bf(float f) {
    union { float f; unsigned u; } v; v.f = f;
    unsigned r = (v.u + 0x7FFFu + ((v.u >> 16) & 1u)) >> 16;
    return (unsigned short)r;
}

// ---------------------------------------------------------------------------
// Kernel 1: Ybf = bf16(X @ W^T).  (proven correct rounds 3-4, unchanged)
// ---------------------------------------------------------------------------
__global__ __launch_bounds__(256) void gemm_xWT_bf(const float* __restrict__ X,
                                                   const float* __restrict__ W,
                                                   unsigned short* __restrict__ Ybf) {
    __shared__ float sA[64][32];
    __shared__ float sWt[32][128];

    const int t  = threadIdx.x;
    const int rg = t >> 5;
    const int cg = t & 31;
    const int base = blockIdx.x * 64;

    float acc[8][4];
    #pragma unroll
    for (int r = 0; r < 8; ++r)
        #pragma unroll
        for (int j = 0; j < 4; ++j) acc[r][j] = 0.f;

    const int arow = t >> 2;
    const int acol = (t & 3) * 8;
    const int grow = min(base + arow, N_NODES - 1);
    const int wo   = t >> 1;
    const int wdh  = (t & 1) * 16;

    for (int kc = 0; kc < D; kc += 32) {
        const float4 x0 = *reinterpret_cast<const float4*>(&X[(size_t)grow * D + kc + acol]);
        const float4 x1 = *reinterpret_cast<const float4*>(&X[(size_t)grow * D + kc + acol + 4]);
        *reinterpret_cast<float4*>(&sA[arow][acol])     = x0;
        *reinterpret_cast<float4*>(&sA[arow][acol + 4]) = x1;

        const float4 w0 = *reinterpret_cast<const float4*>(&W[wo * D + kc + wdh + 0]);
        const float4 w1 = *reinterpret_cast<const float4*>(&W[wo * D + kc + wdh + 4]);
        const float4 w2 = *reinterpret_cast<const float4*>(&W[wo * D + kc + wdh + 8]);
        const float4 w3 = *reinterpret_cast<const float4*>(&W[wo * D + kc + wdh + 12]);
        sWt[wdh +  0][wo] = w0.x; sWt[wdh +  1][wo] = w0.y;
        sWt[wdh +  2][wo] = w0.z; sWt[wdh +  3][wo] = w0.w;
        sWt[wdh +  4][wo] = w1.x; sWt[wdh +  5][wo] = w1.y;
        sWt[wdh +  6][wo] = w1.z; sWt[wdh +  7][wo] = w1.w;
        sWt[wdh +  8][wo] = w2.x; sWt[wdh +  9][wo] = w2.y;
        sWt[wdh + 10][wo] = w2.z; sWt[wdh + 11][wo] = w2.w;
        sWt[wdh + 12][wo] = w3.x; sWt[wdh + 13][wo] = w3.y;
        sWt[wdh + 14][wo] = w3.z; sWt[wdh + 15][wo] = w3.w;
        __syncthreads();

        #pragma unroll
        for (int q = 0; q < 8; ++q) {
            const int d0 = q * 4;
            const float4 wv0 = *reinterpret_cast<const float4*>(&sWt[d0 + 0][cg * 4]);
            const float4 wv1 = *reinterpret_cast<const float4*>(&sWt[d0 + 1][cg * 4]);
            const float4 wv2 = *reinterpret_cast<const float4*>(&sWt[d0 + 2][cg * 4]);
            const float4 wv3 = *reinterpret_cast<const float4*>(&sWt[d0 + 3][cg * 4]);
            #pragma unroll
            for (int r = 0; r < 8; ++r) {
                const float4 av = *reinterpret_cast<const float4*>(&sA[rg * 8 + r][d0]);
                acc[r][0] += av.x * wv0.x; acc[r][0] += av.y * wv1.x;
                acc[r][0] += av.z * wv2.x; acc[r][0] += av.w * wv3.x;
                acc[r][1] += av.x * wv0.y; acc[r][1] += av.y * wv1.y;
                acc[r][1] += av.z * wv2.y; acc[r][1] += av.w * wv3.y;
                acc[r][2] += av.x * wv0.z; acc[r][2] += av.y * wv1.z;
                acc[r][2] += av.z * wv2.z; acc[r][2] += av.w * wv3.z;
                acc[r][3] += av.x * wv0.w; acc[r][3] += av.y * wv1.w;
                acc[r][3] += av.z * wv2.w; acc[r][3] += av.w * wv3.w;
            }
        }
        __syncthreads();
    }

    #pragma unroll
    for (int r = 0; r < 8; ++r) {
        const int row = base + rg * 8 + r;
        if (row < N_NODES) {
            const unsigned lo = (unsigned)f2bf(acc[r][0]) | ((unsigned)f2bf(acc[r][1]) << 16);
            const unsigned hi = (unsigned)f2bf(acc[r][2]) | ((unsigned)f2bf(acc[r][3]) << 16);
            *reinterpret_cast<uint2*>(&Ybf[(size_t)row * D + cg * 4]) = make_uint2(lo, hi);
        }
    }
}

// ---------------------------------------------------------------------------
// Bucket pipeline: bucket = dst>>6 (64 nodes). Records are int2:
//   .x = src | dst_local<<16 | bucket<<22   (16+6+10 bits)
//   .y = float bits of edge weight
// ---------------------------------------------------------------------------
__global__ __launch_bounds__(256) void zero_bcnt(int* __restrict__ bcnt) {
    for (int i = threadIdx.x; i < NBKT; i += 256) bcnt[i] = 0;
}

__global__ __launch_bounds__(256) void bhist(const int* __restrict__ dst,
                                             int* __restrict__ bcnt) {
    const int e = blockIdx.x * 256 + threadIdx.x;
    if (e < N_EDGES) atomicAdd(&bcnt[dst[e] >> 6], 1);
}

// 1-block scan over NBKT(=782) bucket counts -> boffs[0..783] (padded with
// zero-count buckets so boffs[NBKT]=E), and cursor init bcur = boffs.
__global__ __launch_bounds__(256) void bscan(const int* __restrict__ bcnt,
                                             int* __restrict__ boffs,
                                             int* __restrict__ bcur) {
    __shared__ int c[784];
    __shared__ int p[256];
    const int t = threadIdx.x;
    for (int i = t; i < 784; i += 256) c[i] = (i < NBKT) ? bcnt[i] : 0;
    __syncthreads();
    int s0 = 0;
    if (t < 196) s0 = c[4 * t] + c[4 * t + 1] + c[4 * t + 2] + c[4 * t + 3];
    p[t] = s0;
    __syncthreads();
    for (int off = 1; off < 256; off <<= 1) {
        int add = (t >= off) ? p[t - off] : 0;
        __syncthreads();
        p[t] += add;
        __syncthreads();
    }
    if (t < 196) {
        int b0 = p[t] - s0;
        #pragma unroll
        for (int k = 0; k < 4; ++k) {
            const int idx = 4 * t + k;
            if (idx < NBKT) { boffs[idx] = b0; bcur[idx] = b0; }
            else if (idx == NBKT) boffs[idx] = b0;   // = E
            b0 += c[idx];
        }
        if (4 * t + 4 == NBKT) { /* covered above */ }
    }
    if (t == 195) boffs[NBKT] = p[195];  // ensure boffs[782] = total = E
}

// ---------------------------------------------------------------------------
// bin_scatter: each block stages EPB edges, bins them by bucket in LDS,
// grabs one global cursor window per bucket, writes contiguous bursts.
// Removes place_kernel's cross-XCD 8B-scatter false sharing.
// ---------------------------------------------------------------------------
__global__ __launch_bounds__(256) void bin_scatter(const int* __restrict__ src,
                                                   const int* __restrict__ dst,
                                                   const float* __restrict__ ew,
                                                   int* __restrict__ bcur,
                                                   int2* __restrict__ brec) {
    __shared__ int  lcnt[784];
    __shared__ int  loff[784];
    __shared__ int  p[256];
    __shared__ int  gbase[NBKT];
    __shared__ int  lcur[NBKT];
    __shared__ int2 staged[EPB];

    const int t = threadIdx.x;
    const int base = blockIdx.x * EPB;
    const int ec = min(EPB, N_EDGES - base);   // may be <=0 only if grid oversized

    for (int i = t; i < 784; i += 256) lcnt[i] = 0;
    __syncthreads();

    // local histogram
    for (int j = 0; j < EPB / 256; ++j) {
        const int e = base + j * 256 + t;
        if (e < N_EDGES) atomicAdd(&lcnt[dst[e] >> 6], 1);
    }
    __syncthreads();

    // scan 784 counts: group-of-4 partials + 256-scan
    int s0 = 0;
    if (t < 196) s0 = lcnt[4 * t] + lcnt[4 * t + 1] + lcnt[4 * t + 2] + lcnt[4 * t + 3];
    p[t] = s0;
    __syncthreads();
    for (int off = 1; off < 256; off <<= 1) {
        int add = (t >= off) ? p[t - off] : 0;
        __syncthreads();
        p[t] += add;
        __syncthreads();
    }
    if (t < 196) {
        int b0 = p[t] - s0;
        #pragma unroll
        for (int k = 0; k < 4; ++k) {
            loff[4 * t + k] = b0;
            b0 += lcnt[4 * t + k];
        }
    }
    __syncthreads();

    // one global cursor grab per non-empty bucket; init local cursors
    for (int b = t; b < NBKT; b += 256) {
        const int cnt = (b + 1 < 784 ? ((b + 1 < NBKT) ? loff[b + 1] : loff[NBKT - 1] + lcnt[NBKT - 1]) : 0) - loff[b];
        // simpler: cnt = lcnt[b]
        const int c2 = lcnt[b];
        if (c2 > 0) gbase[b] = atomicAdd(&bcur[b], c2);
        lcur[b] = loff[b];
        (void)cnt;
    }
    __syncthreads();

    // place into LDS, bucket-sorted
    for (int j = 0; j < EPB / 256; ++j) {
        const int e = base + j * 256 + t;
        if (e < N_EDGES) {
            const int d = dst[e];
            const int b = d >> 6;
            const int pos = atomicAdd(&lcur[b], 1);
            staged[pos] = make_int2((src[e] & 0xFFFF) | ((d & 63) << 16) | (b << 22),
                                    __float_as_int(ew[e]));
        }
    }
    __syncthreads();

    // write out: contiguous burst per bucket (coalesced within runs)
    for (int i = t; i < ec; i += 256) {
        const int2 r = staged[i];
        const int b = ((unsigned)r.x) >> 22;
        brec[gbase[b] + (i - loff[b])] = r;
    }
}

// ---------------------------------------------------------------------------
// bucket_agg: one block per bucket. Counting-sort the bucket's records in
// LDS (64 counters + wave-shfl scan), then round-3-style aggregate:
// wave handles 16 nodes; per node, 4 edge-groups x 16 lanes x 16B row gather,
// fp32 accumulate, shfl_xor(16/32) reduce, one 512B row write per node.
// ---------------------------------------------------------------------------
__global__ __launch_bounds__(256) void bucket_agg(const unsigned short* __restrict__ Ybf,
                                                  const int2* __restrict__ brec,
                                                  const int* __restrict__ boffs,
                                                  float* __restrict__ out) {
    __shared__ int  cnts[64];
    __shared__ int  offs[65];
    __shared__ int  cur[64];
    __shared__ int2 sorted[CAP];

    const int t = threadIdx.x;
    const int b = blockIdx.x;
    const int base = boffs[b];
    const int cnt = min(boffs[b + 1] - base, CAP);

    if (t < 64) cnts[t] = 0;
    __syncthreads();

    for (int i = t; i < cnt; i += 256)
        atomicAdd(&cnts[(brec[base + i].x >> 16) & 63], 1);
    __syncthreads();

    if (t < 64) {
        int v = cnts[t];
        #pragma unroll
        for (int off = 1; off < 64; off <<= 1) {
            const int u = __shfl_up(v, off, 64);
            if (t >= off) v += u;
        }
        offs[t] = v - cnts[t];
        cur[t]  = v - cnts[t];
        if (t == 63) offs[64] = v;
    }
    __syncthreads();

    for (int i = t; i < cnt; i += 256) {
        const int2 r = brec[base + i];
        const int pos = atomicAdd(&cur[(r.x >> 16) & 63], 1);
        sorted[pos] = r;
    }
    __syncthreads();

    const int wave = t >> 6;
    const int lane = t & 63;
    const int g = lane >> 4;
    const int c = (lane & 15) * 8;

    for (int nl = wave; nl < 64; nl += 4) {
        const int node = b * 64 + nl;
        if (node >= N_NODES) break;
        const int s0 = offs[nl];
        const int s1 = offs[nl + 1];

        float acc[8];
        #pragma unroll
        for (int k = 0; k < 8; ++k) acc[k] = 0.f;

        for (int i = s0 + g; i < s1; i += 4) {
            const int2 r = sorted[i];
            const float w = __int_as_float(r.y);
            const int s = r.x & 0xFFFF;
            const uint4 v = *reinterpret_cast<const uint4*>(&Ybf[(size_t)s * D + c]);
            acc[0] += w * __uint_as_float(v.x << 16);
            acc[1] += w * __uint_as_float(v.x & 0xFFFF0000u);
            acc[2] += w * __uint_as_float(v.y << 16);
            acc[3] += w * __uint_as_float(v.y & 0xFFFF0000u);
            acc[4] += w * __uint_as_float(v.z << 16);
            acc[5] += w * __uint_as_float(v.z & 0xFFFF0000u);
            acc[6] += w * __uint_as_float(v.w << 16);
            acc[7] += w * __uint_as_float(v.w & 0xFFFF0000u);
        }

        #pragma unroll
        for (int k = 0; k < 8; ++k) {
            acc[k] += __shfl_xor(acc[k], 16, 64);
            acc[k] += __shfl_xor(acc[k], 32, 64);
        }

        if (lane < 16) {
            *reinterpret_cast<float4*>(&out[(size_t)node * D + c + 0]) =
                make_float4(acc[0], acc[1], acc[2], acc[3]);
            *reinterpret_cast<float4*>(&out[(size_t)node * D + c + 4]) =
                make_float4(acc[4], acc[5], acc[6], acc[7]);
        }
    }
}

extern "C" void kernel_launch(void* const* d_in, const int* in_sizes, int n_in,
                              void* d_out, int out_size, void* d_ws, size_t ws_size,
                              hipStream_t stream) {
    const float* node_emb    = (const float*)d_in[0];  // [N, 128]
    const float* edge_weight = (const float*)d_in[1];  // [E]
    const int*   src         = (const int*)d_in[2];    // [E]
    const int*   dst         = (const int*)d_in[3];    // [E]
    const float* W           = (const float*)d_in[4];  // [128, 128]

    float* out = (float*)d_out;

    // Workspace layout (bytes):
    //   Ybf   @ 0          : 12,800,000  (N*128 bf16)
    //   bcnt  @ 12,800,000 :      3,128  (NBKT ints)
    //   boffs @ 12,803,200 :      3,136  (NBKT+1 ints, padded)
    //   bcur  @ 12,806,400 :      3,128
    //   brec  @ 12,812,800 :  5,120,000  (E int2 records)
    // total ~17.9 MB
    char* ws = (char*)d_ws;
    unsigned short* Ybf   = (unsigned short*)ws;
    int*            bcnt  = (int*)(ws + 12800000);
    int*            boffs = (int*)(ws + 12803200);
    int*            bcur  = (int*)(ws + 12806400);
    int2*           brec  = (int2*)(ws + 12812800);

    // Ybf = bf16(node_emb @ W^T)   (linear commutes with segment-sum)
    gemm_xWT_bf<<<(N_NODES + 63) / 64, 256, 0, stream>>>(node_emb, W, Ybf);

    // bucketed counting sort of edges by dst-bucket (64 nodes per bucket)
    zero_bcnt  <<<1, 256, 0, stream>>>(bcnt);
    bhist      <<<(N_EDGES + 255) / 256, 256, 0, stream>>>(dst, bcnt);
    bscan      <<<1, 256, 0, stream>>>(bcnt, boffs, bcur);
    bin_scatter<<<NSB, 256, 0, stream>>>(src, dst, edge_weight, bcur, brec);

    // per-bucket in-LDS sort + aggregate
    bucket_agg <<<NBKT, 256, 0, stream>>>(Ybf, brec, boffs, out);
}

// Round 6
// 107.347 us; speedup vs baseline: 2.3977x; 2.3977x over previous
//
#include <hip/hip_runtime.h>

#define N_NODES 50000
#define N_EDGES 640000
#define D 128
#define NBKT 782            // ceil(50000/64) buckets of 64 dst nodes
#define EPB 8192            // edges per bin_scatter block
#define NSB ((N_EDGES + EPB - 1) / EPB)   // 79 scatter blocks
#define CAP 2048            // fixed slot size per bucket (mean 819)

// round-to-nearest-even f32 -> bf16
static __device__ __forceinline__ unsigned short f2bf(float f) {
    union { float f; unsigned u; } v; v.f = f;
    unsigned r = (v.u + 0x7FFFu + ((v.u >> 16) & 1u)) >> 16;
    return (unsigned short)r;
}

// ---------------------------------------------------------------------------
// Kernel 1: Ybf = bf16(X @ W^T).  (proven correct rounds 3-5, unchanged)
// ---------------------------------------------------------------------------
__global__ __launch_bounds__(256) void gemm_xWT_bf(const float* __restrict__ X,
                                                   const float* __restrict__ W,
                                                   unsigned short* __restrict__ Ybf) {
    __shared__ float sA[64][32];
    __shared__ float sWt[32][128];

    const int t  = threadIdx.x;
    const int rg = t >> 5;
    const int cg = t & 31;
    const int base = blockIdx.x * 64;

    float acc[8][4];
    #pragma unroll
    for (int r = 0; r < 8; ++r)
        #pragma unroll
        for (int j = 0; j < 4; ++j) acc[r][j] = 0.f;

    const int arow = t >> 2;
    const int acol = (t & 3) * 8;
    const int grow = min(base + arow, N_NODES - 1);
    const int wo   = t >> 1;
    const int wdh  = (t & 1) * 16;

    for (int kc = 0; kc < D; kc += 32) {
        const float4 x0 = *reinterpret_cast<const float4*>(&X[(size_t)grow * D + kc + acol]);
        const float4 x1 = *reinterpret_cast<const float4*>(&X[(size_t)grow * D + kc + acol + 4]);
        *reinterpret_cast<float4*>(&sA[arow][acol])     = x0;
        *reinterpret_cast<float4*>(&sA[arow][acol + 4]) = x1;

        const float4 w0 = *reinterpret_cast<const float4*>(&W[wo * D + kc + wdh + 0]);
        const float4 w1 = *reinterpret_cast<const float4*>(&W[wo * D + kc + wdh + 4]);
        const float4 w2 = *reinterpret_cast<const float4*>(&W[wo * D + kc + wdh + 8]);
        const float4 w3 = *reinterpret_cast<const float4*>(&W[wo * D + kc + wdh + 12]);
        sWt[wdh +  0][wo] = w0.x; sWt[wdh +  1][wo] = w0.y;
        sWt[wdh +  2][wo] = w0.z; sWt[wdh +  3][wo] = w0.w;
        sWt[wdh +  4][wo] = w1.x; sWt[wdh +  5][wo] = w1.y;
        sWt[wdh +  6][wo] = w1.z; sWt[wdh +  7][wo] = w1.w;
        sWt[wdh +  8][wo] = w2.x; sWt[wdh +  9][wo] = w2.y;
        sWt[wdh + 10][wo] = w2.z; sWt[wdh + 11][wo] = w2.w;
        sWt[wdh + 12][wo] = w3.x; sWt[wdh + 13][wo] = w3.y;
        sWt[wdh + 14][wo] = w3.z; sWt[wdh + 15][wo] = w3.w;
        __syncthreads();

        #pragma unroll
        for (int q = 0; q < 8; ++q) {
            const int d0 = q * 4;
            const float4 wv0 = *reinterpret_cast<const float4*>(&sWt[d0 + 0][cg * 4]);
            const float4 wv1 = *reinterpret_cast<const float4*>(&sWt[d0 + 1][cg * 4]);
            const float4 wv2 = *reinterpret_cast<const float4*>(&sWt[d0 + 2][cg * 4]);
            const float4 wv3 = *reinterpret_cast<const float4*>(&sWt[d0 + 3][cg * 4]);
            #pragma unroll
            for (int r = 0; r < 8; ++r) {
                const float4 av = *reinterpret_cast<const float4*>(&sA[rg * 8 + r][d0]);
                acc[r][0] += av.x * wv0.x; acc[r][0] += av.y * wv1.x;
                acc[r][0] += av.z * wv2.x; acc[r][0] += av.w * wv3.x;
                acc[r][1] += av.x * wv0.y; acc[r][1] += av.y * wv1.y;
                acc[r][1] += av.z * wv2.y; acc[r][1] += av.w * wv3.y;
                acc[r][2] += av.x * wv0.z; acc[r][2] += av.y * wv1.z;
                acc[r][2] += av.z * wv2.z; acc[r][2] += av.w * wv3.z;
                acc[r][3] += av.x * wv0.w; acc[r][3] += av.y * wv1.w;
                acc[r][3] += av.z * wv2.w; acc[r][3] += av.w * wv3.w;
            }
        }
        __syncthreads();
    }

    #pragma unroll
    for (int r = 0; r < 8; ++r) {
        const int row = base + rg * 8 + r;
        if (row < N_NODES) {
            const unsigned lo = (unsigned)f2bf(acc[r][0]) | ((unsigned)f2bf(acc[r][1]) << 16);
            const unsigned hi = (unsigned)f2bf(acc[r][2]) | ((unsigned)f2bf(acc[r][3]) << 16);
            *reinterpret_cast<uint2*>(&Ybf[(size_t)row * D + cg * 4]) = make_uint2(lo, hi);
        }
    }
}

// ---------------------------------------------------------------------------
// Bucket pipeline with FIXED-STRIDE slots: bucket b owns brec[b*CAP ..).
// No global histogram, no global scan. bcur[b] counts records in bucket b.
// Record: .x = src | dst_local<<16 | bucket<<22 ; .y = weight bits.
// ---------------------------------------------------------------------------
__global__ __launch_bounds__(256) void zero_bcur(int* __restrict__ bcur) {
    for (int i = threadIdx.x; i < NBKT; i += 256) bcur[i] = 0;
}

// Each block stages EPB edges: LDS histogram over buckets -> LDS scan ->
// ONE global cursor grab per (block,bucket) pair (<=79 atomics/address) ->
// LDS-sorted staging -> contiguous burst writes into the bucket's slot.
__global__ __launch_bounds__(256) void bin_scatter(const int* __restrict__ src,
                                                   const int* __restrict__ dst,
                                                   const float* __restrict__ ew,
                                                   int* __restrict__ bcur,
                                                   int2* __restrict__ brec) {
    __shared__ int  lcnt[784];
    __shared__ int  loff[784];
    __shared__ int  p[256];
    __shared__ int  gbase[NBKT];
    __shared__ int  lcur[NBKT];
    __shared__ int2 staged[EPB];

    const int t = threadIdx.x;
    const int base = blockIdx.x * EPB;
    const int ec = min(EPB, N_EDGES - base);

    for (int i = t; i < 784; i += 256) lcnt[i] = 0;
    __syncthreads();

    // local histogram (LDS atomics)
    for (int j = 0; j < EPB / 256; ++j) {
        const int e = base + j * 256 + t;
        if (e < N_EDGES) atomicAdd(&lcnt[dst[e] >> 6], 1);
    }
    __syncthreads();

    // scan 784 counts: group-of-4 partials + 256-wide scan
    int s0 = 0;
    if (t < 196) s0 = lcnt[4 * t] + lcnt[4 * t + 1] + lcnt[4 * t + 2] + lcnt[4 * t + 3];
    p[t] = s0;
    __syncthreads();
    for (int off = 1; off < 256; off <<= 1) {
        int add = (t >= off) ? p[t - off] : 0;
        __syncthreads();
        p[t] += add;
        __syncthreads();
    }
    if (t < 196) {
        int b0 = p[t] - s0;
        #pragma unroll
        for (int k = 0; k < 4; ++k) {
            loff[4 * t + k] = b0;
            b0 += lcnt[4 * t + k];
        }
    }
    __syncthreads();

    // one global window grab per non-empty bucket
    for (int b = t; b < NBKT; b += 256) {
        const int c2 = lcnt[b];
        if (c2 > 0) gbase[b] = (b << 11) + atomicAdd(&bcur[b], c2);
        lcur[b] = loff[b];
    }
    __syncthreads();

    // place into LDS, bucket-grouped
    for (int j = 0; j < EPB / 256; ++j) {
        const int e = base + j * 256 + t;
        if (e < N_EDGES) {
            const int d = dst[e];
            const int b = d >> 6;
            const int pos = atomicAdd(&lcur[b], 1);
            staged[pos] = make_int2((src[e] & 0xFFFF) | ((d & 63) << 16) | (b << 22),
                                    __float_as_int(ew[e]));
        }
    }
    __syncthreads();

    // contiguous burst write per bucket run (overflow-guarded)
    for (int i = t; i < ec; i += 256) {
        const int2 r = staged[i];
        const int b = ((unsigned)r.x) >> 22;
        const int idx = gbase[b] + (i - loff[b]);
        if (idx < ((b + 1) << 11)) brec[idx] = r;
    }
}

// ---------------------------------------------------------------------------
// bucket_agg: one block per bucket. In-LDS counting sort by dst_local, then
// per-node aggregate: 4 edge-groups x 16 lanes x 16B bf16 row gather, fp32
// accumulate, shfl_xor(16/32) reduce, one 512B row write per node.
// ---------------------------------------------------------------------------
__global__ __launch_bounds__(256) void bucket_agg(const unsigned short* __restrict__ Ybf,
                                                  const int2* __restrict__ brec,
                                                  const int* __restrict__ bcur,
                                                  float* __restrict__ out) {
    __shared__ int  cnts[64];
    __shared__ int  offs[65];
    __shared__ int  cur[64];
    __shared__ int2 sorted[CAP];

    const int t = threadIdx.x;
    const int b = blockIdx.x;
    const int base = b << 11;           // b * CAP
    const int cnt = min(bcur[b], CAP);

    if (t < 64) cnts[t] = 0;
    __syncthreads();

    for (int i = t; i < cnt; i += 256)
        atomicAdd(&cnts[(brec[base + i].x >> 16) & 63], 1);
    __syncthreads();

    if (t < 64) {
        int v = cnts[t];
        #pragma unroll
        for (int off = 1; off < 64; off <<= 1) {
            const int u = __shfl_up(v, off, 64);
            if (t >= off) v += u;
        }
        offs[t] = v - cnts[t];
        cur[t]  = v - cnts[t];
        if (t == 63) offs[64] = v;
    }
    __syncthreads();

    for (int i = t; i < cnt; i += 256) {
        const int2 r = brec[base + i];
        const int pos = atomicAdd(&cur[(r.x >> 16) & 63], 1);
        sorted[pos] = r;
    }
    __syncthreads();

    const int wave = t >> 6;
    const int lane = t & 63;
    const int g = lane >> 4;
    const int c = (lane & 15) * 8;

    for (int nl = wave; nl < 64; nl += 4) {
        const int node = b * 64 + nl;
        if (node >= N_NODES) break;
        const int s0 = offs[nl];
        const int s1 = offs[nl + 1];

        float acc[8];
        #pragma unroll
        for (int k = 0; k < 8; ++k) acc[k] = 0.f;

        for (int i = s0 + g; i < s1; i += 4) {
            const int2 r = sorted[i];
            const float w = __int_as_float(r.y);
            const int s = r.x & 0xFFFF;
            const uint4 v = *reinterpret_cast<const uint4*>(&Ybf[(size_t)s * D + c]);
            acc[0] += w * __uint_as_float(v.x << 16);
            acc[1] += w * __uint_as_float(v.x & 0xFFFF0000u);
            acc[2] += w * __uint_as_float(v.y << 16);
            acc[3] += w * __uint_as_float(v.y & 0xFFFF0000u);
            acc[4] += w * __uint_as_float(v.z << 16);
            acc[5] += w * __uint_as_float(v.z & 0xFFFF0000u);
            acc[6] += w * __uint_as_float(v.w << 16);
            acc[7] += w * __uint_as_float(v.w & 0xFFFF0000u);
        }

        #pragma unroll
        for (int k = 0; k < 8; ++k) {
            acc[k] += __shfl_xor(acc[k], 16, 64);
            acc[k] += __shfl_xor(acc[k], 32, 64);
        }

        if (lane < 16) {
            *reinterpret_cast<float4*>(&out[(size_t)node * D + c + 0]) =
                make_float4(acc[0], acc[1], acc[2], acc[3]);
            *reinterpret_cast<float4*>(&out[(size_t)node * D + c + 4]) =
                make_float4(acc[4], acc[5], acc[6], acc[7]);
        }
    }
}

extern "C" void kernel_launch(void* const* d_in, const int* in_sizes, int n_in,
                              void* d_out, int out_size, void* d_ws, size_t ws_size,
                              hipStream_t stream) {
    const float* node_emb    = (const float*)d_in[0];  // [N, 128]
    const float* edge_weight = (const float*)d_in[1];  // [E]
    const int*   src         = (const int*)d_in[2];    // [E]
    const int*   dst         = (const int*)d_in[3];    // [E]
    const float* W           = (const float*)d_in[4];  // [128, 128]

    float* out = (float*)d_out;

    // Workspace layout (bytes):
    //   Ybf  @ 0          : 12,800,000  (N*128 bf16)
    //   bcur @ 12,800,000 :      3,128  (NBKT ints)
    //   brec @ 12,806,144 : 12,812,288  (NBKT*CAP int2, fixed stride)
    // total ~25.6 MB
    char* ws = (char*)d_ws;
    unsigned short* Ybf  = (unsigned short*)ws;
    int*            bcur = (int*)(ws + 12800000);
    int2*           brec = (int2*)(ws + 12806144);

    // Ybf = bf16(node_emb @ W^T)   (linear commutes with segment-sum)
    gemm_xWT_bf<<<(N_NODES + 63) / 64, 256, 0, stream>>>(node_emb, W, Ybf);

    // fixed-stride bucketed sort (no global hist/scan)
    zero_bcur  <<<1, 256, 0, stream>>>(bcur);
    bin_scatter<<<NSB, 256, 0, stream>>>(src, dst, edge_weight, bcur, brec);

    // per-bucket in-LDS sort + aggregate
    bucket_agg <<<NBKT, 256, 0, stream>>>(Ybf, brec, bcur, out);
}

// Round 7
// 85.845 us; speedup vs baseline: 2.9982x; 1.2505x over previous
//
#include <hip/hip_runtime.h>

#define N_NODES 50000
#define N_EDGES 640000
#define D 128
#define NBKT 782            // ceil(50000/64) buckets of 64 dst nodes
#define EPB 2048            // edges per bin_scatter block
#define SCT 1024            // bin_scatter threads per block
#define NSB ((N_EDGES + EPB - 1) / EPB)   // 313 scatter blocks
#define CAP 2048            // fixed slot size per bucket (mean 819)

// round-to-nearest-even f32 -> bf16
static __device__ __forceinline__ unsigned short f2bf(float f) {
    union { float f; unsigned u; } v; v.f = f;
    unsigned r = (v.u + 0x7FFFu + ((v.u >> 16) & 1u)) >> 16;
    return (unsigned short)r;
}

// ---------------------------------------------------------------------------
// Kernel 1: Ybf = bf16(X @ W^T).  (proven correct rounds 3-6, unchanged)
// ---------------------------------------------------------------------------
__global__ __launch_bounds__(256) void gemm_xWT_bf(const float* __restrict__ X,
                                                   const float* __restrict__ W,
                                                   unsigned short* __restrict__ Ybf) {
    __shared__ float sA[64][32];
    __shared__ float sWt[32][128];

    const int t  = threadIdx.x;
    const int rg = t >> 5;
    const int cg = t & 31;
    const int base = blockIdx.x * 64;

    float acc[8][4];
    #pragma unroll
    for (int r = 0; r < 8; ++r)
        #pragma unroll
        for (int j = 0; j < 4; ++j) acc[r][j] = 0.f;

    const int arow = t >> 2;
    const int acol = (t & 3) * 8;
    const int grow = min(base + arow, N_NODES - 1);
    const int wo   = t >> 1;
    const int wdh  = (t & 1) * 16;

    for (int kc = 0; kc < D; kc += 32) {
        const float4 x0 = *reinterpret_cast<const float4*>(&X[(size_t)grow * D + kc + acol]);
        const float4 x1 = *reinterpret_cast<const float4*>(&X[(size_t)grow * D + kc + acol + 4]);
        *reinterpret_cast<float4*>(&sA[arow][acol])     = x0;
        *reinterpret_cast<float4*>(&sA[arow][acol + 4]) = x1;

        const float4 w0 = *reinterpret_cast<const float4*>(&W[wo * D + kc + wdh + 0]);
        const float4 w1 = *reinterpret_cast<const float4*>(&W[wo * D + kc + wdh + 4]);
        const float4 w2 = *reinterpret_cast<const float4*>(&W[wo * D + kc + wdh + 8]);
        const float4 w3 = *reinterpret_cast<const float4*>(&W[wo * D + kc + wdh + 12]);
        sWt[wdh +  0][wo] = w0.x; sWt[wdh +  1][wo] = w0.y;
        sWt[wdh +  2][wo] = w0.z; sWt[wdh +  3][wo] = w0.w;
        sWt[wdh +  4][wo] = w1.x; sWt[wdh +  5][wo] = w1.y;
        sWt[wdh +  6][wo] = w1.z; sWt[wdh +  7][wo] = w1.w;
        sWt[wdh +  8][wo] = w2.x; sWt[wdh +  9][wo] = w2.y;
        sWt[wdh + 10][wo] = w2.z; sWt[wdh + 11][wo] = w2.w;
        sWt[wdh + 12][wo] = w3.x; sWt[wdh + 13][wo] = w3.y;
        sWt[wdh + 14][wo] = w3.z; sWt[wdh + 15][wo] = w3.w;
        __syncthreads();

        #pragma unroll
        for (int q = 0; q < 8; ++q) {
            const int d0 = q * 4;
            const float4 wv0 = *reinterpret_cast<const float4*>(&sWt[d0 + 0][cg * 4]);
            const float4 wv1 = *reinterpret_cast<const float4*>(&sWt[d0 + 1][cg * 4]);
            const float4 wv2 = *reinterpret_cast<const float4*>(&sWt[d0 + 2][cg * 4]);
            const float4 wv3 = *reinterpret_cast<const float4*>(&sWt[d0 + 3][cg * 4]);
            #pragma unroll
            for (int r = 0; r < 8; ++r) {
                const float4 av = *reinterpret_cast<const float4*>(&sA[rg * 8 + r][d0]);
                acc[r][0] += av.x * wv0.x; acc[r][0] += av.y * wv1.x;
                acc[r][0] += av.z * wv2.x; acc[r][0] += av.w * wv3.x;
                acc[r][1] += av.x * wv0.y; acc[r][1] += av.y * wv1.y;
                acc[r][1] += av.z * wv2.y; acc[r][1] += av.w * wv3.y;
                acc[r][2] += av.x * wv0.z; acc[r][2] += av.y * wv1.z;
                acc[r][2] += av.z * wv2.z; acc[r][2] += av.w * wv3.z;
                acc[r][3] += av.x * wv0.w; acc[r][3] += av.y * wv1.w;
                acc[r][3] += av.z * wv2.w; acc[r][3] += av.w * wv3.w;
            }
        }
        __syncthreads();
    }

    #pragma unroll
    for (int r = 0; r < 8; ++r) {
        const int row = base + rg * 8 + r;
        if (row < N_NODES) {
            const unsigned lo = (unsigned)f2bf(acc[r][0]) | ((unsigned)f2bf(acc[r][1]) << 16);
            const unsigned hi = (unsigned)f2bf(acc[r][2]) | ((unsigned)f2bf(acc[r][3]) << 16);
            *reinterpret_cast<uint2*>(&Ybf[(size_t)row * D + cg * 4]) = make_uint2(lo, hi);
        }
    }
}

// ---------------------------------------------------------------------------
// Bucket pipeline with FIXED-STRIDE slots: bucket b owns brec[b*CAP ..).
// Record: .x = src | dst_local<<16 | bucket<<22 ; .y = weight bits.
// (src < 50000 < 2^16 after masking: 50000 <= 65535, fits.)
// ---------------------------------------------------------------------------
__global__ __launch_bounds__(256) void zero_bcur(int* __restrict__ bcur) {
    for (int i = threadIdx.x; i < NBKT; i += 256) bcur[i] = 0;
}

// 1024 threads x 2048 edges: per-thread serial depth = 2 (was 32), 313 blocks
// (was 79) -> latency-bound section gets ~16x more wave parallelism.
__global__ __launch_bounds__(SCT) void bin_scatter(const int* __restrict__ src,
                                                   const int* __restrict__ dst,
                                                   const float* __restrict__ ew,
                                                   int* __restrict__ bcur,
                                                   int2* __restrict__ brec) {
    __shared__ int  lcnt[784];
    __shared__ int  loff[784];
    __shared__ int  p[256];
    __shared__ int  gbase[NBKT];
    __shared__ int  lcur[NBKT];
    __shared__ int2 staged[EPB];

    const int t = threadIdx.x;
    const int base = blockIdx.x * EPB;
    const int ec = min(EPB, N_EDGES - base);

    for (int i = t; i < 784; i += SCT) lcnt[i] = 0;
    __syncthreads();

    // local histogram (LDS atomics)
    #pragma unroll
    for (int j = 0; j < EPB / SCT; ++j) {
        const int e = base + j * SCT + t;
        if (e < N_EDGES) atomicAdd(&lcnt[dst[e] >> 6], 1);
    }
    __syncthreads();

    // scan 784 counts on threads 0..255 (group-of-4 partials + 256-wide scan)
    int s0 = 0;
    if (t < 196) s0 = lcnt[4 * t] + lcnt[4 * t + 1] + lcnt[4 * t + 2] + lcnt[4 * t + 3];
    if (t < 256) p[t] = s0;
    __syncthreads();
    for (int off = 1; off < 256; off <<= 1) {
        int add = 0;
        if (t < 256 && t >= off) add = p[t - off];
        __syncthreads();
        if (t < 256) p[t] += add;
        __syncthreads();
    }
    if (t < 196) {
        int b0 = p[t] - s0;
        #pragma unroll
        for (int k = 0; k < 4; ++k) {
            loff[4 * t + k] = b0;
            b0 += lcnt[4 * t + k];
        }
    }
    __syncthreads();

    // one global window grab per non-empty bucket
    for (int b = t; b < NBKT; b += SCT) {
        const int c2 = lcnt[b];
        if (c2 > 0) gbase[b] = (b << 11) + atomicAdd(&bcur[b], c2);
        lcur[b] = loff[b];
    }
    __syncthreads();

    // place into LDS, bucket-grouped
    #pragma unroll
    for (int j = 0; j < EPB / SCT; ++j) {
        const int e = base + j * SCT + t;
        if (e < N_EDGES) {
            const int d = dst[e];
            const int b = d >> 6;
            const int pos = atomicAdd(&lcur[b], 1);
            staged[pos] = make_int2((src[e] & 0xFFFF) | ((d & 63) << 16) | (b << 22),
                                    __float_as_int(ew[e]));
        }
    }
    __syncthreads();

    // contiguous burst write per bucket run (overflow-guarded)
    for (int i = t; i < ec; i += SCT) {
        const int2 r = staged[i];
        const int b = ((unsigned)r.x) >> 22;
        const int idx = gbase[b] + (i - loff[b]);
        if (idx < ((b + 1) << 11)) brec[idx] = r;
    }
}

// ---------------------------------------------------------------------------
// bucket_agg: one block per bucket. In-LDS counting sort by dst_local, then
// per-node aggregate: 4 edge-groups x 16 lanes x 16B bf16 row gather, fp32
// accumulate, shfl_xor(16/32) reduce, one 512B row write per node.
// ---------------------------------------------------------------------------
__global__ __launch_bounds__(256) void bucket_agg(const unsigned short* __restrict__ Ybf,
                                                  const int2* __restrict__ brec,
                                                  const int* __restrict__ bcur,
                                                  float* __restrict__ out) {
    __shared__ int  cnts[64];
    __shared__ int  offs[65];
    __shared__ int  cur[64];
    __shared__ int2 sorted[CAP];

    const int t = threadIdx.x;
    const int b = blockIdx.x;
    const int base = b << 11;           // b * CAP
    const int cnt = min(bcur[b], CAP);

    if (t < 64) cnts[t] = 0;
    __syncthreads();

    for (int i = t; i < cnt; i += 256)
        atomicAdd(&cnts[(brec[base + i].x >> 16) & 63], 1);
    __syncthreads();

    if (t < 64) {
        int v = cnts[t];
        #pragma unroll
        for (int off = 1; off < 64; off <<= 1) {
            const int u = __shfl_up(v, off, 64);
            if (t >= off) v += u;
        }
        offs[t] = v - cnts[t];
        cur[t]  = v - cnts[t];
        if (t == 63) offs[64] = v;
    }
    __syncthreads();

    for (int i = t; i < cnt; i += 256) {
        const int2 r = brec[base + i];
        const int pos = atomicAdd(&cur[(r.x >> 16) & 63], 1);
        sorted[pos] = r;
    }
    __syncthreads();

    const int wave = t >> 6;
    const int lane = t & 63;
    const int g = lane >> 4;
    const int c = (lane & 15) * 8;

    for (int nl = wave; nl < 64; nl += 4) {
        const int node = b * 64 + nl;
        if (node >= N_NODES) break;
        const int s0 = offs[nl];
        const int s1 = offs[nl + 1];

        float acc[8];
        #pragma unroll
        for (int k = 0; k < 8; ++k) acc[k] = 0.f;

        for (int i = s0 + g; i < s1; i += 4) {
            const int2 r = sorted[i];
            const float w = __int_as_float(r.y);
            const int s = r.x & 0xFFFF;
            const uint4 v = *reinterpret_cast<const uint4*>(&Ybf[(size_t)s * D + c]);
            acc[0] += w * __uint_as_float(v.x << 16);
            acc[1] += w * __uint_as_float(v.x & 0xFFFF0000u);
            acc[2] += w * __uint_as_float(v.y << 16);
            acc[3] += w * __uint_as_float(v.y & 0xFFFF0000u);
            acc[4] += w * __uint_as_float(v.z << 16);
            acc[5] += w * __uint_as_float(v.z & 0xFFFF0000u);
            acc[6] += w * __uint_as_float(v.w << 16);
            acc[7] += w * __uint_as_float(v.w & 0xFFFF0000u);
        }

        #pragma unroll
        for (int k = 0; k < 8; ++k) {
            acc[k] += __shfl_xor(acc[k], 16, 64);
            acc[k] += __shfl_xor(acc[k], 32, 64);
        }

        if (lane < 16) {
            *reinterpret_cast<float4*>(&out[(size_t)node * D + c + 0]) =
                make_float4(acc[0], acc[1], acc[2], acc[3]);
            *reinterpret_cast<float4*>(&out[(size_t)node * D + c + 4]) =
                make_float4(acc[4], acc[5], acc[6], acc[7]);
        }
    }
}

extern "C" void kernel_launch(void* const* d_in, const int* in_sizes, int n_in,
                              void* d_out, int out_size, void* d_ws, size_t ws_size,
                              hipStream_t stream) {
    const float* node_emb    = (const float*)d_in[0];  // [N, 128]
    const float* edge_weight = (const float*)d_in[1];  // [E]
    const int*   src         = (const int*)d_in[2];    // [E]
    const int*   dst         = (const int*)d_in[3];    // [E]
    const float* W           = (const float*)d_in[4];  // [128, 128]

    float* out = (float*)d_out;

    // Workspace layout (bytes):
    //   Ybf  @ 0          : 12,800,000  (N*128 bf16)
    //   bcur @ 12,800,000 :      3,128  (NBKT ints)
    //   brec @ 12,806,144 : 12,812,288  (NBKT*CAP int2, fixed stride)
    char* ws = (char*)d_ws;
    unsigned short* Ybf  = (unsigned short*)ws;
    int*            bcur = (int*)(ws + 12800000);
    int2*           brec = (int2*)(ws + 12806144);

    // Ybf = bf16(node_emb @ W^T)   (linear commutes with segment-sum)
    gemm_xWT_bf<<<(N_NODES + 63) / 64, 256, 0, stream>>>(node_emb, W, Ybf);

    // fixed-stride bucketed sort (no global hist/scan)
    zero_bcur  <<<1, 256, 0, stream>>>(bcur);
    bin_scatter<<<NSB, SCT, 0, stream>>>(src, dst, edge_weight, bcur, brec);

    // per-bucket in-LDS sort + aggregate
    bucket_agg <<<NBKT, 256, 0, stream>>>(Ybf, brec, bcur, out);
}

// Round 8
// 71.834 us; speedup vs baseline: 3.5830x; 1.1950x over previous
//
#include <hip/hip_runtime.h>

#define N_NODES 50000
#define N_EDGES 640000
#define D 128
#define NBKT 782            // ceil(50000/64) buckets of 64 dst nodes
#define EPB 2048            // edges per bin_scatter block
#define SCT 1024            // bin_scatter threads per block
#define NSB ((N_EDGES + EPB - 1) / EPB)   // 313 scatter blocks
#define CAP 2048            // fixed slot size per bucket (mean 819)

typedef __attribute__((ext_vector_type(8))) short bf16x8;
typedef __attribute__((ext_vector_type(4))) float f32x4;

// round-to-nearest-even f32 -> bf16
static __device__ __forceinline__ unsigned short f2bf(float f) {
    union { float f; unsigned u; } v; v.f = f;
    unsigned r = (v.u + 0x7FFFu + ((v.u >> 16) & 1u)) >> 16;
    return (unsigned short)r;
}

// ---------------------------------------------------------------------------
// Kernel 1: Ybf = bf16(X @ W^T) via MFMA 16x16x32 bf16.
// Block = 64 rows x 128 cols, 256 threads = 4 waves x 16 rows.
// B-fragments (B = W^T, so B[k][n] = W[n][k]) are pre-packed in LDS in exact
// register order: sB[ct][kk][lane][j] = W[ct*16+(lane&15)][kk*32+(lane>>4)*8+j].
// A-fragments built from global X: lane holds X[base+w*16+(lane&15)][k-major 8].
// C/D mapping (m89-verified): col = lane&15, row = (lane>>4)*4 + reg.
// ---------------------------------------------------------------------------
__global__ __launch_bounds__(256) void gemm_mfma_bf(const float* __restrict__ X,
                                                    const float* __restrict__ W,
                                                    unsigned short* __restrict__ Ybf) {
    __shared__ unsigned short sB[8][4][64][8];   // 32 KiB

    const int t    = threadIdx.x;
    const int wave = t >> 6;
    const int lane = t & 63;
    const int base = blockIdx.x * 64;

    // Pack B fragments: 2048 (ct,kk,lane) triples, 8 per thread.
    for (int idx = t; idx < 2048; idx += 256) {
        const int ln = idx & 63;
        const int kk = (idx >> 6) & 3;
        const int ct = idx >> 8;
        const int n  = ct * 16 + (ln & 15);
        const int k0 = kk * 32 + (ln >> 4) * 8;
        const float4 wa = *reinterpret_cast<const float4*>(&W[n * D + k0]);
        const float4 wb = *reinterpret_cast<const float4*>(&W[n * D + k0 + 4]);
        unsigned short* d8 = &sB[ct][kk][ln][0];
        d8[0] = f2bf(wa.x); d8[1] = f2bf(wa.y); d8[2] = f2bf(wa.z); d8[3] = f2bf(wa.w);
        d8[4] = f2bf(wb.x); d8[5] = f2bf(wb.y); d8[6] = f2bf(wb.z); d8[7] = f2bf(wb.w);
    }

    // A fragments straight from global (rows clamped; stores guarded below).
    const int arow = base + wave * 16 + (lane & 15);
    const int grow = min(arow, N_NODES - 1);
    bf16x8 a[4];
    #pragma unroll
    for (int kk = 0; kk < 4; ++kk) {
        const int k0 = kk * 32 + (lane >> 4) * 8;
        const float4 xa = *reinterpret_cast<const float4*>(&X[(size_t)grow * D + k0]);
        const float4 xb = *reinterpret_cast<const float4*>(&X[(size_t)grow * D + k0 + 4]);
        a[kk][0] = (short)f2bf(xa.x); a[kk][1] = (short)f2bf(xa.y);
        a[kk][2] = (short)f2bf(xa.z); a[kk][3] = (short)f2bf(xa.w);
        a[kk][4] = (short)f2bf(xb.x); a[kk][5] = (short)f2bf(xb.y);
        a[kk][6] = (short)f2bf(xb.z); a[kk][7] = (short)f2bf(xb.w);
    }
    __syncthreads();

    f32x4 acc[8];
    #pragma unroll
    for (int ct = 0; ct < 8; ++ct) acc[ct] = (f32x4){0.f, 0.f, 0.f, 0.f};

    #pragma unroll
    for (int ct = 0; ct < 8; ++ct) {
        #pragma unroll
        for (int kk = 0; kk < 4; ++kk) {
            const bf16x8 b = *reinterpret_cast<const bf16x8*>(&sB[ct][kk][lane][0]);
            acc[ct] = __builtin_amdgcn_mfma_f32_16x16x32_bf16(a[kk], b, acc[ct], 0, 0, 0);
        }
    }

    // Epilogue: row = base + wave*16 + (lane>>4)*4 + reg, col = ct*16 + (lane&15)
    const int orow0 = base + wave * 16 + (lane >> 4) * 4;
    const int ocol  = lane & 15;
    #pragma unroll
    for (int r = 0; r < 4; ++r) {
        const int row = orow0 + r;
        if (row < N_NODES) {
            #pragma unroll
            for (int ct = 0; ct < 8; ++ct)
                Ybf[(size_t)row * D + ct * 16 + ocol] = f2bf(acc[ct][r]);
        }
    }
}

// ---------------------------------------------------------------------------
// Bucket pipeline with FIXED-STRIDE slots: bucket b owns brec[b*CAP ..).
// Record: .x = src | dst_local<<16 | bucket<<22 ; .y = weight bits.
// ---------------------------------------------------------------------------
__global__ __launch_bounds__(256) void zero_bcur(int* __restrict__ bcur) {
    for (int i = threadIdx.x; i < NBKT; i += 256) bcur[i] = 0;
}

__global__ __launch_bounds__(SCT) void bin_scatter(const int* __restrict__ src,
                                                   const int* __restrict__ dst,
                                                   const float* __restrict__ ew,
                                                   int* __restrict__ bcur,
                                                   int2* __restrict__ brec) {
    __shared__ int  lcnt[784];
    __shared__ int  loff[784];
    __shared__ int  p[256];
    __shared__ int  gbase[NBKT];
    __shared__ int  lcur[NBKT];
    __shared__ int2 staged[EPB];

    const int t = threadIdx.x;
    const int base = blockIdx.x * EPB;
    const int ec = min(EPB, N_EDGES - base);

    for (int i = t; i < 784; i += SCT) lcnt[i] = 0;
    __syncthreads();

    #pragma unroll
    for (int j = 0; j < EPB / SCT; ++j) {
        const int e = base + j * SCT + t;
        if (e < N_EDGES) atomicAdd(&lcnt[dst[e] >> 6], 1);
    }
    __syncthreads();

    int s0 = 0;
    if (t < 196) s0 = lcnt[4 * t] + lcnt[4 * t + 1] + lcnt[4 * t + 2] + lcnt[4 * t + 3];
    if (t < 256) p[t] = s0;
    __syncthreads();
    for (int off = 1; off < 256; off <<= 1) {
        int add = 0;
        if (t < 256 && t >= off) add = p[t - off];
        __syncthreads();
        if (t < 256) p[t] += add;
        __syncthreads();
    }
    if (t < 196) {
        int b0 = p[t] - s0;
        #pragma unroll
        for (int k = 0; k < 4; ++k) {
            loff[4 * t + k] = b0;
            b0 += lcnt[4 * t + k];
        }
    }
    __syncthreads();

    for (int b = t; b < NBKT; b += SCT) {
        const int c2 = lcnt[b];
        if (c2 > 0) gbase[b] = (b << 11) + atomicAdd(&bcur[b], c2);
        lcur[b] = loff[b];
    }
    __syncthreads();

    #pragma unroll
    for (int j = 0; j < EPB / SCT; ++j) {
        const int e = base + j * SCT + t;
        if (e < N_EDGES) {
            const int d = dst[e];
            const int b = d >> 6;
            const int pos = atomicAdd(&lcur[b], 1);
            staged[pos] = make_int2((src[e] & 0xFFFF) | ((d & 63) << 16) | (b << 22),
                                    __float_as_int(ew[e]));
        }
    }
    __syncthreads();

    for (int i = t; i < ec; i += SCT) {
        const int2 r = staged[i];
        const int b = ((unsigned)r.x) >> 22;
        const int idx = gbase[b] + (i - loff[b]);
        if (idx < ((b + 1) << 11)) brec[idx] = r;
    }
}

// ---------------------------------------------------------------------------
// bucket_agg: one block per bucket. In-LDS counting sort by dst_local, then
// per-node aggregate (4 edge-groups x 16 lanes x 16B bf16 row gather).
// ---------------------------------------------------------------------------
__global__ __launch_bounds__(256) void bucket_agg(const unsigned short* __restrict__ Ybf,
                                                  const int2* __restrict__ brec,
                                                  const int* __restrict__ bcur,
                                                  float* __restrict__ out) {
    __shared__ int  cnts[64];
    __shared__ int  offs[65];
    __shared__ int  cur[64];
    __shared__ int2 sorted[CAP];

    const int t = threadIdx.x;
    const int b = blockIdx.x;
    const int base = b << 11;
    const int cnt = min(bcur[b], CAP);

    if (t < 64) cnts[t] = 0;
    __syncthreads();

    for (int i = t; i < cnt; i += 256)
        atomicAdd(&cnts[(brec[base + i].x >> 16) & 63], 1);
    __syncthreads();

    if (t < 64) {
        int v = cnts[t];
        #pragma unroll
        for (int off = 1; off < 64; off <<= 1) {
            const int u = __shfl_up(v, off, 64);
            if (t >= off) v += u;
        }
        offs[t] = v - cnts[t];
        cur[t]  = v - cnts[t];
        if (t == 63) offs[64] = v;
    }
    __syncthreads();

    for (int i = t; i < cnt; i += 256) {
        const int2 r = brec[base + i];
        const int pos = atomicAdd(&cur[(r.x >> 16) & 63], 1);
        sorted[pos] = r;
    }
    __syncthreads();

    const int wave = t >> 6;
    const int lane = t & 63;
    const int g = lane >> 4;
    const int c = (lane & 15) * 8;

    for (int nl = wave; nl < 64; nl += 4) {
        const int node = b * 64 + nl;
        if (node >= N_NODES) break;
        const int s0 = offs[nl];
        const int s1 = offs[nl + 1];

        float acc[8];
        #pragma unroll
        for (int k = 0; k < 8; ++k) acc[k] = 0.f;

        for (int i = s0 + g; i < s1; i += 4) {
            const int2 r = sorted[i];
            const float w = __int_as_float(r.y);
            const int s = r.x & 0xFFFF;
            const uint4 v = *reinterpret_cast<const uint4*>(&Ybf[(size_t)s * D + c]);
            acc[0] += w * __uint_as_float(v.x << 16);
            acc[1] += w * __uint_as_float(v.x & 0xFFFF0000u);
            acc[2] += w * __uint_as_float(v.y << 16);
            acc[3] += w * __uint_as_float(v.y & 0xFFFF0000u);
            acc[4] += w * __uint_as_float(v.z << 16);
            acc[5] += w * __uint_as_float(v.z & 0xFFFF0000u);
            acc[6] += w * __uint_as_float(v.w << 16);
            acc[7] += w * __uint_as_float(v.w & 0xFFFF0000u);
        }

        #pragma unroll
        for (int k = 0; k < 8; ++k) {
            acc[k] += __shfl_xor(acc[k], 16, 64);
            acc[k] += __shfl_xor(acc[k], 32, 64);
        }

        if (lane < 16) {
            *reinterpret_cast<float4*>(&out[(size_t)node * D + c + 0]) =
                make_float4(acc[0], acc[1], acc[2], acc[3]);
            *reinterpret_cast<float4*>(&out[(size_t)node * D + c + 4]) =
                make_float4(acc[4], acc[5], acc[6], acc[7]);
        }
    }
}

extern "C" void kernel_launch(void* const* d_in, const int* in_sizes, int n_in,
                              void* d_out, int out_size, void* d_ws, size_t ws_size,
                              hipStream_t stream) {
    const float* node_emb    = (const float*)d_in[0];  // [N, 128]
    const float* edge_weight = (const float*)d_in[1];  // [E]
    const int*   src         = (const int*)d_in[2];    // [E]
    const int*   dst         = (const int*)d_in[3];    // [E]
    const float* W           = (const float*)d_in[4];  // [128, 128]

    float* out = (float*)d_out;

    // Workspace layout (bytes):
    //   Ybf  @ 0          : 12,800,000  (N*128 bf16)
    //   bcur @ 12,800,000 :      3,128  (NBKT ints)
    //   brec @ 12,806,144 : 12,812,288  (NBKT*CAP int2, fixed stride)
    char* ws = (char*)d_ws;
    unsigned short* Ybf  = (unsigned short*)ws;
    int*            bcur = (int*)(ws + 12800000);
    int2*           brec = (int2*)(ws + 12806144);

    // Ybf = bf16(node_emb @ W^T) via MFMA  (linear commutes with segment-sum)
    gemm_mfma_bf<<<(N_NODES + 63) / 64, 256, 0, stream>>>(node_emb, W, Ybf);

    // fixed-stride bucketed sort (no global hist/scan)
    zero_bcur  <<<1, 256, 0, stream>>>(bcur);
    bin_scatter<<<NSB, SCT, 0, stream>>>(src, dst, edge_weight, bcur, brec);

    // per-bucket in-LDS sort + aggregate
    bucket_agg <<<NBKT, 256, 0, stream>>>(Ybf, brec, bcur, out);
}

// Round 9
// 64.461 us; speedup vs baseline: 3.9928x; 1.1144x over previous
//
#include <hip/hip_runtime.h>

#define N_NODES 50000
#define N_EDGES 640000
#define D 128
#define NBKT 782            // ceil(50000/64) buckets of 64 dst nodes
#define EPB 2048            // edges per scatter block
#define NSB ((N_EDGES + EPB - 1) / EPB)   // 313 scatter blocks
#define GB 196              // gemm super-blocks (4 x 64-row tiles each; 784 tiles >= 782)
#define CAP 2048            // fixed slot size per bucket (mean 819)

typedef __attribute__((ext_vector_type(8))) short bf16x8;
typedef __attribute__((ext_vector_type(4))) float f32x4;

// round-to-nearest-even f32 -> bf16
static __device__ __forceinline__ unsigned short f2bf(float f) {
    union { float f; unsigned u; } v; v.f = f;
    unsigned r = (v.u + 0x7FFFu + ((v.u >> 16) & 1u)) >> 16;
    return (unsigned short)r;
}

// ---------------------------------------------------------------------------
// Fused kernel: blocks [0, GB) run the MFMA GEMM (Ybf = bf16(X @ W^T));
// blocks [GB, GB+NSB) run the bucketed edge scatter. The two phases are
// data-independent; merging them lets the CUs overlap what stream order
// would otherwise serialize (no events allowed under graph capture).
// LDS: single 32 KB arena, re-pointered per branch.
// ---------------------------------------------------------------------------
__global__ __launch_bounds__(1024) void fused_gemm_scatter(
        const float* __restrict__ X, const float* __restrict__ W,
        const int* __restrict__ src, const int* __restrict__ dst,
        const float* __restrict__ ew,
        unsigned short* __restrict__ Ybf,
        int* __restrict__ bcur, int2* __restrict__ brec) {
    __shared__ __align__(16) char smem[32768];
    const int t = threadIdx.x;

    if (blockIdx.x < GB) {
        // ------------------- GEMM branch (4 tiles of 64 rows) -------------------
        // sB[ct][kk][lane][j] = bf16(W[ct*16+(lane&15)][kk*32+(lane>>4)*8+j])
        unsigned short (*sB)[4][64][8] = (unsigned short (*)[4][64][8])smem;

        // Pack W fragments once per block (shared by all 4 tiles).
        for (int idx = t; idx < 2048; idx += 1024) {
            const int ln = idx & 63;
            const int kk = (idx >> 6) & 3;
            const int ct = idx >> 8;
            const int n  = ct * 16 + (ln & 15);
            const int k0 = kk * 32 + (ln >> 4) * 8;
            const float4 wa = *reinterpret_cast<const float4*>(&W[n * D + k0]);
            const float4 wb = *reinterpret_cast<const float4*>(&W[n * D + k0 + 4]);
            unsigned short* d8 = &sB[ct][kk][ln][0];
            d8[0] = f2bf(wa.x); d8[1] = f2bf(wa.y); d8[2] = f2bf(wa.z); d8[3] = f2bf(wa.w);
            d8[4] = f2bf(wb.x); d8[5] = f2bf(wb.y); d8[6] = f2bf(wb.z); d8[7] = f2bf(wb.w);
        }

        const int s    = t >> 8;            // sub-tile 0..3
        const int wv   = (t >> 6) & 3;      // wave within sub-tile
        const int lane = t & 63;
        const int tile = blockIdx.x * 4 + s;
        const int base = tile * 64;

        // A fragments straight from global (rows clamped; stores guarded).
        const int arow = base + wv * 16 + (lane & 15);
        const int grow = min(arow, N_NODES - 1);
        bf16x8 a[4];
        #pragma unroll
        for (int kk = 0; kk < 4; ++kk) {
            const int k0 = kk * 32 + (lane >> 4) * 8;
            const float4 xa = *reinterpret_cast<const float4*>(&X[(size_t)grow * D + k0]);
            const float4 xb = *reinterpret_cast<const float4*>(&X[(size_t)grow * D + k0 + 4]);
            a[kk][0] = (short)f2bf(xa.x); a[kk][1] = (short)f2bf(xa.y);
            a[kk][2] = (short)f2bf(xa.z); a[kk][3] = (short)f2bf(xa.w);
            a[kk][4] = (short)f2bf(xb.x); a[kk][5] = (short)f2bf(xb.y);
            a[kk][6] = (short)f2bf(xb.z); a[kk][7] = (short)f2bf(xb.w);
        }
        __syncthreads();

        f32x4 acc[8];
        #pragma unroll
        for (int ct = 0; ct < 8; ++ct) acc[ct] = (f32x4){0.f, 0.f, 0.f, 0.f};

        #pragma unroll
        for (int ct = 0; ct < 8; ++ct) {
            #pragma unroll
            for (int kk = 0; kk < 4; ++kk) {
                const bf16x8 b = *reinterpret_cast<const bf16x8*>(&sB[ct][kk][lane][0]);
                acc[ct] = __builtin_amdgcn_mfma_f32_16x16x32_bf16(a[kk], b, acc[ct], 0, 0, 0);
            }
        }

        // C/D mapping (m89): col = ct*16 + (lane&15), row = base+wv*16+(lane>>4)*4+reg
        const int orow0 = base + wv * 16 + (lane >> 4) * 4;
        const int ocol  = lane & 15;
        #pragma unroll
        for (int r = 0; r < 4; ++r) {
            const int row = orow0 + r;
            if (row < N_NODES) {
                #pragma unroll
                for (int ct = 0; ct < 8; ++ct)
                    Ybf[(size_t)row * D + ct * 16 + ocol] = f2bf(acc[ct][r]);
            }
        }
    } else {
        // ------------------- Scatter branch (proven round-7 body) -------------------
        int*  lcnt   = (int*)(smem);            // 784 ints
        int*  loff   = (int*)(smem + 3136);     // 784 ints
        int*  p      = (int*)(smem + 6272);     // 256 ints
        int*  gbase  = (int*)(smem + 7296);     // NBKT ints
        int*  lcur   = (int*)(smem + 10424);    // NBKT ints
        int2* staged = (int2*)(smem + 13552);   // EPB int2 (16 KB) -> total 29936 B

        const int base = (blockIdx.x - GB) * EPB;
        const int ec = min(EPB, N_EDGES - base);

        for (int i = t; i < 784; i += 1024) lcnt[i] = 0;
        __syncthreads();

        // local histogram (LDS atomics); depth 2 per thread
        #pragma unroll
        for (int j = 0; j < EPB / 1024; ++j) {
            const int e = base + j * 1024 + t;
            if (e < N_EDGES) atomicAdd(&lcnt[dst[e] >> 6], 1);
        }
        __syncthreads();

        // scan 784 counts on threads 0..255
        int s0 = 0;
        if (t < 196) s0 = lcnt[4 * t] + lcnt[4 * t + 1] + lcnt[4 * t + 2] + lcnt[4 * t + 3];
        if (t < 256) p[t] = s0;
        __syncthreads();
        for (int off = 1; off < 256; off <<= 1) {
            int add = 0;
            if (t < 256 && t >= off) add = p[t - off];
            __syncthreads();
            if (t < 256) p[t] += add;
            __syncthreads();
        }
        if (t < 196) {
            int b0 = p[t] - s0;
            #pragma unroll
            for (int k = 0; k < 4; ++k) {
                loff[4 * t + k] = b0;
                b0 += lcnt[4 * t + k];
            }
        }
        __syncthreads();

        // one global window grab per non-empty bucket
        for (int b = t; b < NBKT; b += 1024) {
            const int c2 = lcnt[b];
            if (c2 > 0) gbase[b] = (b << 11) + atomicAdd(&bcur[b], c2);
            lcur[b] = loff[b];
        }
        __syncthreads();

        // place into LDS, bucket-grouped
        #pragma unroll
        for (int j = 0; j < EPB / 1024; ++j) {
            const int e = base + j * 1024 + t;
            if (e < N_EDGES) {
                const int d = dst[e];
                const int b = d >> 6;
                const int pos = atomicAdd(&lcur[b], 1);
                staged[pos] = make_int2((src[e] & 0xFFFF) | ((d & 63) << 16) | (b << 22),
                                        __float_as_int(ew[e]));
            }
        }
        __syncthreads();

        // contiguous burst write per bucket run (overflow-guarded)
        for (int i = t; i < ec; i += 1024) {
            const int2 r = staged[i];
            const int b = ((unsigned)r.x) >> 22;
            const int idx = gbase[b] + (i - loff[b]);
            if (idx < ((b + 1) << 11)) brec[idx] = r;
        }
    }
}

// ---------------------------------------------------------------------------
// bucket_agg: one block per bucket. In-LDS counting sort by dst_local, then
// per-node aggregate (4 edge-groups x 16 lanes x 16B bf16 row gather), fp32
// accumulate, shfl_xor(16/32) reduce, one 512B row write per node.
// (Proven rounds 5-8, unchanged.)
// ---------------------------------------------------------------------------
__global__ __launch_bounds__(256) void bucket_agg(const unsigned short* __restrict__ Ybf,
                                                  const int2* __restrict__ brec,
                                                  const int* __restrict__ bcur,
                                                  float* __restrict__ out) {
    __shared__ int  cnts[64];
    __shared__ int  offs[65];
    __shared__ int  cur[64];
    __shared__ int2 sorted[CAP];

    const int t = threadIdx.x;
    const int b = blockIdx.x;
    const int base = b << 11;
    const int cnt = min(bcur[b], CAP);

    if (t < 64) cnts[t] = 0;
    __syncthreads();

    for (int i = t; i < cnt; i += 256)
        atomicAdd(&cnts[(brec[base + i].x >> 16) & 63], 1);
    __syncthreads();

    if (t < 64) {
        int v = cnts[t];
        #pragma unroll
        for (int off = 1; off < 64; off <<= 1) {
            const int u = __shfl_up(v, off, 64);
            if (t >= off) v += u;
        }
        offs[t] = v - cnts[t];
        cur[t]  = v - cnts[t];
        if (t == 63) offs[64] = v;
    }
    __syncthreads();

    for (int i = t; i < cnt; i += 256) {
        const int2 r = brec[base + i];
        const int pos = atomicAdd(&cur[(r.x >> 16) & 63], 1);
        sorted[pos] = r;
    }
    __syncthreads();

    const int wave = t >> 6;
    const int lane = t & 63;
    const int g = lane >> 4;
    const int c = (lane & 15) * 8;

    for (int nl = wave; nl < 64; nl += 4) {
        const int node = b * 64 + nl;
        if (node >= N_NODES) break;
        const int s0 = offs[nl];
        const int s1 = offs[nl + 1];

        float acc[8];
        #pragma unroll
        for (int k = 0; k < 8; ++k) acc[k] = 0.f;

        for (int i = s0 + g; i < s1; i += 4) {
            const int2 r = sorted[i];
            const float w = __int_as_float(r.y);
            const int s = r.x & 0xFFFF;
            const uint4 v = *reinterpret_cast<const uint4*>(&Ybf[(size_t)s * D + c]);
            acc[0] += w * __uint_as_float(v.x << 16);
            acc[1] += w * __uint_as_float(v.x & 0xFFFF0000u);
            acc[2] += w * __uint_as_float(v.y << 16);
            acc[3] += w * __uint_as_float(v.y & 0xFFFF0000u);
            acc[4] += w * __uint_as_float(v.z << 16);
            acc[5] += w * __uint_as_float(v.z & 0xFFFF0000u);
            acc[6] += w * __uint_as_float(v.w << 16);
            acc[7] += w * __uint_as_float(v.w & 0xFFFF0000u);
        }

        #pragma unroll
        for (int k = 0; k < 8; ++k) {
            acc[k] += __shfl_xor(acc[k], 16, 64);
            acc[k] += __shfl_xor(acc[k], 32, 64);
        }

        if (lane < 16) {
            *reinterpret_cast<float4*>(&out[(size_t)node * D + c + 0]) =
                make_float4(acc[0], acc[1], acc[2], acc[3]);
            *reinterpret_cast<float4*>(&out[(size_t)node * D + c + 4]) =
                make_float4(acc[4], acc[5], acc[6], acc[7]);
        }
    }
}

extern "C" void kernel_launch(void* const* d_in, const int* in_sizes, int n_in,
                              void* d_out, int out_size, void* d_ws, size_t ws_size,
                              hipStream_t stream) {
    const float* node_emb    = (const float*)d_in[0];  // [N, 128]
    const float* edge_weight = (const float*)d_in[1];  // [E]
    const int*   src         = (const int*)d_in[2];    // [E]
    const int*   dst         = (const int*)d_in[3];    // [E]
    const float* W           = (const float*)d_in[4];  // [128, 128]

    float* out = (float*)d_out;

    // Workspace layout (bytes):
    //   Ybf  @ 0          : 12,800,000  (N*128 bf16)
    //   bcur @ 12,800,000 :      3,128  (NBKT ints)
    //   brec @ 12,806,144 : 12,812,288  (NBKT*CAP int2, fixed stride)
    char* ws = (char*)d_ws;
    unsigned short* Ybf  = (unsigned short*)ws;
    int*            bcur = (int*)(ws + 12800000);
    int2*           brec = (int2*)(ws + 12806144);

    hipMemsetAsync(bcur, 0, NBKT * sizeof(int), stream);

    // GEMM (blocks 0..195) runs concurrently with edge scatter (blocks 196..508)
    fused_gemm_scatter<<<GB + NSB, 1024, 0, stream>>>(node_emb, W, src, dst,
                                                      edge_weight, Ybf, bcur, brec);

    // per-bucket in-LDS sort + aggregate
    bucket_agg<<<NBKT, 256, 0, stream>>>(Ybf, brec, bcur, out);
}

// Round 10
// 55.993 us; speedup vs baseline: 4.5967x; 1.1512x over previous
//
#include <hip/hip_runtime.h>

#define N_NODES 50000
#define N_EDGES 640000
#define D 128
#define NBKT 782            // ceil(50000/64) buckets of 64 dst nodes
#define EPB 2048            // edges per scatter block
#define NSB ((N_EDGES + EPB - 1) / EPB)   // 313 scatter blocks
#define GB 196              // gemm super-blocks (4 x 64-row tiles each)
#define CAP 2048            // fixed slot size per bucket (mean 819)

typedef __attribute__((ext_vector_type(8))) short bf16x8;
typedef __attribute__((ext_vector_type(4))) float f32x4;

// round-to-nearest-even f32 -> bf16
static __device__ __forceinline__ unsigned short f2bf(float f) {
    union { float f; unsigned u; } v; v.f = f;
    unsigned r = (v.u + 0x7FFFu + ((v.u >> 16) & 1u)) >> 16;
    return (unsigned short)r;
}

// ---------------------------------------------------------------------------
// Fused kernel: blocks [0, GB) run the MFMA GEMM (Ybf = bf16(X @ W^T));
// blocks [GB, GB+NSB) run the bucketed edge scatter. (Proven round 9.)
// ---------------------------------------------------------------------------
__global__ __launch_bounds__(1024) void fused_gemm_scatter(
        const float* __restrict__ X, const float* __restrict__ W,
        const int* __restrict__ src, const int* __restrict__ dst,
        const float* __restrict__ ew,
        unsigned short* __restrict__ Ybf,
        int* __restrict__ bcur, int2* __restrict__ brec) {
    __shared__ __align__(16) char smem[32768];
    const int t = threadIdx.x;

    if (blockIdx.x < GB) {
        // ------------------- GEMM branch (4 tiles of 64 rows) -------------------
        unsigned short (*sB)[4][64][8] = (unsigned short (*)[4][64][8])smem;

        for (int idx = t; idx < 2048; idx += 1024) {
            const int ln = idx & 63;
            const int kk = (idx >> 6) & 3;
            const int ct = idx >> 8;
            const int n  = ct * 16 + (ln & 15);
            const int k0 = kk * 32 + (ln >> 4) * 8;
            const float4 wa = *reinterpret_cast<const float4*>(&W[n * D + k0]);
            const float4 wb = *reinterpret_cast<const float4*>(&W[n * D + k0 + 4]);
            unsigned short* d8 = &sB[ct][kk][ln][0];
            d8[0] = f2bf(wa.x); d8[1] = f2bf(wa.y); d8[2] = f2bf(wa.z); d8[3] = f2bf(wa.w);
            d8[4] = f2bf(wb.x); d8[5] = f2bf(wb.y); d8[6] = f2bf(wb.z); d8[7] = f2bf(wb.w);
        }

        const int s    = t >> 8;            // sub-tile 0..3
        const int wv   = (t >> 6) & 3;      // wave within sub-tile
        const int lane = t & 63;
        const int tile = blockIdx.x * 4 + s;
        const int base = tile * 64;

        const int arow = base + wv * 16 + (lane & 15);
        const int grow = min(arow, N_NODES - 1);
        bf16x8 a[4];
        #pragma unroll
        for (int kk = 0; kk < 4; ++kk) {
            const int k0 = kk * 32 + (lane >> 4) * 8;
            const float4 xa = *reinterpret_cast<const float4*>(&X[(size_t)grow * D + k0]);
            const float4 xb = *reinterpret_cast<const float4*>(&X[(size_t)grow * D + k0 + 4]);
            a[kk][0] = (short)f2bf(xa.x); a[kk][1] = (short)f2bf(xa.y);
            a[kk][2] = (short)f2bf(xa.z); a[kk][3] = (short)f2bf(xa.w);
            a[kk][4] = (short)f2bf(xb.x); a[kk][5] = (short)f2bf(xb.y);
            a[kk][6] = (short)f2bf(xb.z); a[kk][7] = (short)f2bf(xb.w);
        }
        __syncthreads();

        f32x4 acc[8];
        #pragma unroll
        for (int ct = 0; ct < 8; ++ct) acc[ct] = (f32x4){0.f, 0.f, 0.f, 0.f};

        #pragma unroll
        for (int ct = 0; ct < 8; ++ct) {
            #pragma unroll
            for (int kk = 0; kk < 4; ++kk) {
                const bf16x8 b = *reinterpret_cast<const bf16x8*>(&sB[ct][kk][lane][0]);
                acc[ct] = __builtin_amdgcn_mfma_f32_16x16x32_bf16(a[kk], b, acc[ct], 0, 0, 0);
            }
        }

        const int orow0 = base + wv * 16 + (lane >> 4) * 4;
        const int ocol  = lane & 15;
        #pragma unroll
        for (int r = 0; r < 4; ++r) {
            const int row = orow0 + r;
            if (row < N_NODES) {
                #pragma unroll
                for (int ct = 0; ct < 8; ++ct)
                    Ybf[(size_t)row * D + ct * 16 + ocol] = f2bf(acc[ct][r]);
            }
        }
    } else {
        // ------------------- Scatter branch (proven round-7/9 body) -------------------
        int*  lcnt   = (int*)(smem);            // 784 ints
        int*  loff   = (int*)(smem + 3136);     // 784 ints
        int*  p      = (int*)(smem + 6272);     // 256 ints
        int*  gbase  = (int*)(smem + 7296);     // NBKT ints
        int*  lcur   = (int*)(smem + 10424);    // NBKT ints
        int2* staged = (int2*)(smem + 13552);   // EPB int2 (16 KB)

        const int base = (blockIdx.x - GB) * EPB;
        const int ec = min(EPB, N_EDGES - base);

        for (int i = t; i < 784; i += 1024) lcnt[i] = 0;
        __syncthreads();

        #pragma unroll
        for (int j = 0; j < EPB / 1024; ++j) {
            const int e = base + j * 1024 + t;
            if (e < N_EDGES) atomicAdd(&lcnt[dst[e] >> 6], 1);
        }
        __syncthreads();

        int s0 = 0;
        if (t < 196) s0 = lcnt[4 * t] + lcnt[4 * t + 1] + lcnt[4 * t + 2] + lcnt[4 * t + 3];
        if (t < 256) p[t] = s0;
        __syncthreads();
        for (int off = 1; off < 256; off <<= 1) {
            int add = 0;
            if (t < 256 && t >= off) add = p[t - off];
            __syncthreads();
            if (t < 256) p[t] += add;
            __syncthreads();
        }
        if (t < 196) {
            int b0 = p[t] - s0;
            #pragma unroll
            for (int k = 0; k < 4; ++k) {
                loff[4 * t + k] = b0;
                b0 += lcnt[4 * t + k];
            }
        }
        __syncthreads();

        for (int b = t; b < NBKT; b += 1024) {
            const int c2 = lcnt[b];
            if (c2 > 0) gbase[b] = (b << 11) + atomicAdd(&bcur[b], c2);
            lcur[b] = loff[b];
        }
        __syncthreads();

        #pragma unroll
        for (int j = 0; j < EPB / 1024; ++j) {
            const int e = base + j * 1024 + t;
            if (e < N_EDGES) {
                const int d = dst[e];
                const int b = d >> 6;
                const int pos = atomicAdd(&lcur[b], 1);
                staged[pos] = make_int2((src[e] & 0xFFFF) | ((d & 63) << 16) | (b << 22),
                                        __float_as_int(ew[e]));
            }
        }
        __syncthreads();

        for (int i = t; i < ec; i += 1024) {
            const int2 r = staged[i];
            const int b = ((unsigned)r.x) >> 22;
            const int idx = gbase[b] + (i - loff[b]);
            if (idx < ((b + 1) << 11)) brec[idx] = r;
        }
    }
}

// ---------------------------------------------------------------------------
// bucket_agg: one block per bucket, now 512 threads = 8 waves (was 4) and a
// 2x-unrolled gather loop -> ~4x more outstanding 16B gathers machine-wide.
// Wave w handles nodes {w, w+8, ..., w+56}. Inner loop per 16-lane group g:
// edges i and i+4 loaded as two independent uint4s per pass.
// ---------------------------------------------------------------------------
__global__ __launch_bounds__(512) void bucket_agg(const unsigned short* __restrict__ Ybf,
                                                  const int2* __restrict__ brec,
                                                  const int* __restrict__ bcur,
                                                  float* __restrict__ out) {
    __shared__ int  cnts[64];
    __shared__ int  offs[65];
    __shared__ int  cur[64];
    __shared__ int2 sorted[CAP];

    const int t = threadIdx.x;
    const int b = blockIdx.x;
    const int base = b << 11;
    const int cnt = min(bcur[b], CAP);

    if (t < 64) cnts[t] = 0;
    __syncthreads();

    for (int i = t; i < cnt; i += 512)
        atomicAdd(&cnts[(brec[base + i].x >> 16) & 63], 1);
    __syncthreads();

    if (t < 64) {
        int v = cnts[t];
        #pragma unroll
        for (int off = 1; off < 64; off <<= 1) {
            const int u = __shfl_up(v, off, 64);
            if (t >= off) v += u;
        }
        offs[t] = v - cnts[t];
        cur[t]  = v - cnts[t];
        if (t == 63) offs[64] = v;
    }
    __syncthreads();

    for (int i = t; i < cnt; i += 512) {
        const int2 r = brec[base + i];
        const int pos = atomicAdd(&cur[(r.x >> 16) & 63], 1);
        sorted[pos] = r;
    }
    __syncthreads();

    const int wave = t >> 6;          // 0..7
    const int lane = t & 63;
    const int g = lane >> 4;          // edge sub-slot 0..3
    const int c = (lane & 15) * 8;    // 8 output cols

    for (int nl = wave; nl < 64; nl += 8) {
        const int node = b * 64 + nl;
        if (node >= N_NODES) break;
        const int s0 = offs[nl];
        const int s1 = offs[nl + 1];

        float acc[8];
        #pragma unroll
        for (int k = 0; k < 8; ++k) acc[k] = 0.f;

        int i = s0 + g;
        // 2x unrolled: edges i and i+4 in flight together
        for (; i + 4 < s1; i += 8) {
            const int2 r0 = sorted[i];
            const int2 r1 = sorted[i + 4];
            const float w0 = __int_as_float(r0.y);
            const float w1 = __int_as_float(r1.y);
            const uint4 v0 = *reinterpret_cast<const uint4*>(&Ybf[(size_t)(r0.x & 0xFFFF) * D + c]);
            const uint4 v1 = *reinterpret_cast<const uint4*>(&Ybf[(size_t)(r1.x & 0xFFFF) * D + c]);
            acc[0] += w0 * __uint_as_float(v0.x << 16);
            acc[1] += w0 * __uint_as_float(v0.x & 0xFFFF0000u);
            acc[2] += w0 * __uint_as_float(v0.y << 16);
            acc[3] += w0 * __uint_as_float(v0.y & 0xFFFF0000u);
            acc[4] += w0 * __uint_as_float(v0.z << 16);
            acc[5] += w0 * __uint_as_float(v0.z & 0xFFFF0000u);
            acc[6] += w0 * __uint_as_float(v0.w << 16);
            acc[7] += w0 * __uint_as_float(v0.w & 0xFFFF0000u);
            acc[0] += w1 * __uint_as_float(v1.x << 16);
            acc[1] += w1 * __uint_as_float(v1.x & 0xFFFF0000u);
            acc[2] += w1 * __uint_as_float(v1.y << 16);
            acc[3] += w1 * __uint_as_float(v1.y & 0xFFFF0000u);
            acc[4] += w1 * __uint_as_float(v1.z << 16);
            acc[5] += w1 * __uint_as_float(v1.z & 0xFFFF0000u);
            acc[6] += w1 * __uint_as_float(v1.w << 16);
            acc[7] += w1 * __uint_as_float(v1.w & 0xFFFF0000u);
        }
        if (i < s1) {
            const int2 r = sorted[i];
            const float w = __int_as_float(r.y);
            const uint4 v = *reinterpret_cast<const uint4*>(&Ybf[(size_t)(r.x & 0xFFFF) * D + c]);
            acc[0] += w * __uint_as_float(v.x << 16);
            acc[1] += w * __uint_as_float(v.x & 0xFFFF0000u);
            acc[2] += w * __uint_as_float(v.y << 16);
            acc[3] += w * __uint_as_float(v.y & 0xFFFF0000u);
            acc[4] += w * __uint_as_float(v.z << 16);
            acc[5] += w * __uint_as_float(v.z & 0xFFFF0000u);
            acc[6] += w * __uint_as_float(v.w << 16);
            acc[7] += w * __uint_as_float(v.w & 0xFFFF0000u);
        }

        #pragma unroll
        for (int k = 0; k < 8; ++k) {
            acc[k] += __shfl_xor(acc[k], 16, 64);
            acc[k] += __shfl_xor(acc[k], 32, 64);
        }

        if (lane < 16) {
            *reinterpret_cast<float4*>(&out[(size_t)node * D + c + 0]) =
                make_float4(acc[0], acc[1], acc[2], acc[3]);
            *reinterpret_cast<float4*>(&out[(size_t)node * D + c + 4]) =
                make_float4(acc[4], acc[5], acc[6], acc[7]);
        }
    }
}

extern "C" void kernel_launch(void* const* d_in, const int* in_sizes, int n_in,
                              void* d_out, int out_size, void* d_ws, size_t ws_size,
                              hipStream_t stream) {
    const float* node_emb    = (const float*)d_in[0];  // [N, 128]
    const float* edge_weight = (const float*)d_in[1];  // [E]
    const int*   src         = (const int*)d_in[2];    // [E]
    const int*   dst         = (const int*)d_in[3];    // [E]
    const float* W           = (const float*)d_in[4];  // [128, 128]

    float* out = (float*)d_out;

    // Workspace layout (bytes):
    //   Ybf  @ 0          : 12,800,000  (N*128 bf16)
    //   bcur @ 12,800,000 :      3,128  (NBKT ints)
    //   brec @ 12,806,144 : 12,812,288  (NBKT*CAP int2, fixed stride)
    char* ws = (char*)d_ws;
    unsigned short* Ybf  = (unsigned short*)ws;
    int*            bcur = (int*)(ws + 12800000);
    int2*           brec = (int2*)(ws + 12806144);

    hipMemsetAsync(bcur, 0, NBKT * sizeof(int), stream);

    // GEMM (blocks 0..195) runs concurrently with edge scatter (blocks 196..508)
    fused_gemm_scatter<<<GB + NSB, 1024, 0, stream>>>(node_emb, W, src, dst,
                                                      edge_weight, Ybf, bcur, brec);

    // per-bucket in-LDS sort + aggregate (8 waves, 2x-unrolled gather)
    bucket_agg<<<NBKT, 512, 0, stream>>>(Ybf, brec, bcur, out);
}